// Round 7
// baseline (232.358 us; speedup 1.0000x reference)
//
#include <hip/hip_runtime.h>
#include <hip/hip_bf16.h>

// CentralSpecificModel: per-species 2-layer MLP (256 -> 1024 -> 256), 4 species,
// N=65536 rows, fp32 in/out. Bucket rows by species; fused per-64-row-tile
// kernel does GEMM1+silu+GEMM2 with bf16 MFMA (16x16x32), swapped operands
// (weights as A, X/H as B -> H^T/Y^T), batched B-frag prefetch, dbuf Hs.
// R9: the non-fused gap (~96us) has been stable across ALL rounds; attack it.
// prep + count merged into ONE launch (removes a launch-drain boundary) with
// ATOMIC-FREE deterministic bucketing: count block b tallies rows [0, b*2048)
// itself (int4 loads, per-thread tallies, LDS reduce) to get its global bases;
// ranks via the proven ballot machinery; block 31 writes cnt totals as plain
// stores. No atomics, no cnt pre-zeroing, no cross-block ordering (R4's memset
// suspect eliminated). Fused kernel byte-identical to R8 (123.8us: cvt_pk
// packing + s_setprio around MFMA clusters on the proven R3 structure).

#define N_ATOMS 65536
#define D_IN 256
#define D_HID 1024
#define D_OUT 256
#define TPS 1024   // max 64-row tiles per species (worst case: all rows one species)

typedef __attribute__((ext_vector_type(8))) short short8;
typedef __attribute__((ext_vector_type(4))) float float4e;
typedef __attribute__((ext_vector_type(2))) unsigned uint2e;
typedef __attribute__((ext_vector_type(4))) unsigned uint4e;

// ws layout (bytes):
//   [0, 256)           cnt[4] padded: cnt[s] at int offset s*16 (64B apart)
//   [256, 1048832)     bucket[4][65536] int
//   [1048832, 3145984) W1 swizzled bf16 fragments (4*256*1024)
//   [3145984, 5243136) W2 swizzled bf16 fragments (4*1024*256)
#define WS_BUCKET_OFF 256
#define WS_W1_OFF 1048832
#define WS_W2_OFF 3145984

#define CF_BLOCKS 32
#define CF_ITERS 8
#define CF_ROWS (CF_ITERS * 256)   // 2048 rows per count block

__device__ __forceinline__ short f2bf(float f) {
  unsigned u = __builtin_bit_cast(unsigned, f);
  unsigned r = (u + 0x7FFFu + ((u >> 16) & 1u)) >> 16;   // round-to-nearest-even
  return (short)r;
}

// Two f32 -> packed 2x bf16 in one instruction (low half = a, high half = b).
__device__ __forceinline__ unsigned cvt_pk_bf16(float a, float b) {
  unsigned r;
  asm("v_cvt_pk_bf16_f32 %0, %1, %2" : "=v"(r) : "v"(a), "v"(b));
  return r;
}

// Merged prep + bucketing, one launch, no atomics, no pre-zeroed memory.
// Blocks 0..31: deterministic bucketing of 2048 rows each. Block b computes
// its global per-species base by tallying rows [0, b*2048) directly (int4
// loads, L2-resident: 256KB total), then scatters its own rows with
// ballot-derived ranks. Block 31 writes cnt[s] totals (plain stores).
// Blocks 32..1055: weight swizzle fp32 -> bf16 MFMA B-fragment order.
// B-frag (16x16x32): lane l holds B[k0 + 8*(l>>4) + j][nt*16 + (l&15)], j=0..7.
__global__ __launch_bounds__(256) void prep_count_kernel(
    const float* __restrict__ W1, const float* __restrict__ W2,
    short* __restrict__ w1sw, short* __restrict__ w2sw,
    const int* __restrict__ species, int* __restrict__ cnt,
    int* __restrict__ bucket) {
  int tid = threadIdx.x;

  if (blockIdx.x < CF_BLOCKS) {
    // ---- deterministic bucketing ----
    __shared__ int red[4];                 // prefix counts (global base)
    __shared__ int wcnt[CF_ITERS][4][4];   // [iter][wave][species]
    __shared__ int wb[CF_ITERS][4][4];     // exclusive prefix within block
    int b = blockIdx.x;
    if (tid < 4) red[tid] = 0;
    __syncthreads();

    // Phase 1: tally rows [0, b*2048) -> per-thread counts -> LDS reduce.
    int pc0 = 0, pc1 = 0, pc2 = 0, pc3 = 0;
    int nPrefix = b * CF_ROWS;             // multiple of 2048, int4-aligned
    for (int base = tid * 4; base < nPrefix; base += 1024) {
      int4 v = *(const int4*)(species + base);
      int s0 = v.x & 3, s1 = v.y & 3, s2 = v.z & 3, s3 = v.w & 3;
      pc0 += (s0 == 0) + (s1 == 0) + (s2 == 0) + (s3 == 0);
      pc1 += (s0 == 1) + (s1 == 1) + (s2 == 1) + (s3 == 1);
      pc2 += (s0 == 2) + (s1 == 2) + (s2 == 2) + (s3 == 2);
      pc3 += (s0 == 3) + (s1 == 3) + (s2 == 3) + (s3 == 3);
    }
    if (pc0) atomicAdd(&red[0], pc0);      // LDS atomics (block-local)
    if (pc1) atomicAdd(&red[1], pc1);
    if (pc2) atomicAdd(&red[2], pc2);
    if (pc3) atomicAdd(&red[3], pc3);

    // Phase 2: own 2048 rows — ballot counts + per-lane ranks.
    int lane = tid & 63, wid = tid >> 6;
    int sv[CF_ITERS], rk[CF_ITERS];
    unsigned long long below = (1ull << lane) - 1ull;
    int base_i = b * CF_ROWS;
    #pragma unroll
    for (int it = 0; it < CF_ITERS; ++it) {
      int s = species[base_i + it * 256 + tid] & 3;
      sv[it] = s;
      unsigned long long m0 = __ballot(s == 0);
      unsigned long long m1 = __ballot(s == 1);
      unsigned long long m2 = __ballot(s == 2);
      unsigned long long m3 = __ballot(s == 3);
      unsigned long long ms = (s == 0) ? m0 : (s == 1) ? m1 : (s == 2) ? m2 : m3;
      rk[it] = __popcll(ms & below);
      if (lane == 0) {
        wcnt[it][wid][0] = __popcll(m0);
        wcnt[it][wid][1] = __popcll(m1);
        wcnt[it][wid][2] = __popcll(m2);
        wcnt[it][wid][3] = __popcll(m3);
      }
    }
    __syncthreads();
    if (tid < 4) {
      int ss = tid, run = 0;
      for (int it = 0; it < CF_ITERS; ++it)
        for (int w = 0; w < 4; ++w) {
          wb[it][w][ss] = run;
          run += wcnt[it][w][ss];
        }
      if (b == CF_BLOCKS - 1) cnt[ss * 16] = red[ss] + run;  // totals, plain store
    }
    __syncthreads();
    #pragma unroll
    for (int it = 0; it < CF_ITERS; ++it) {
      int ss = sv[it];
      bucket[ss * N_ATOMS + red[ss] + wb[it][wid][ss] + rk[it]] = base_i + it * 256 + tid;
    }
    return;
  }

  // ---- weight swizzle ----
  int gid = (blockIdx.x - CF_BLOCKS) * 256 + tid;   // 262144 threads
  int lane = gid & 63;
  int lr = lane & 15;
  int lk = (lane >> 4) * 8;
  if (gid < 131072) {            // W1: [4][256][1024], NT=64, KS=8
    int ks = (gid >> 6) & 7;
    int nt = (gid >> 9) & 63;
    int s  = gid >> 15;
    const float* src = W1 + ((size_t)(s * 256 + ks * 32 + lk)) * 1024 + nt * 16 + lr;
    short8 v;
    for (int j = 0; j < 8; ++j) v[j] = f2bf(src[(size_t)j * 1024]);
    *(short8*)(w1sw + (size_t)gid * 8) = v;
  } else {                       // W2: [4][1024][256], NT=16, KS=32
    int g = gid - 131072;
    int kt = (g >> 6) & 31;
    int nt = (g >> 11) & 15;
    int s  = g >> 15;
    const float* src = W2 + ((size_t)(s * 1024 + kt * 32 + lk)) * 256 + nt * 16 + lr;
    short8 v;
    for (int j = 0; j < 8; ++j) v[j] = f2bf(src[(size_t)j * 256]);
    *(short8*)(w2sw + (size_t)g * 8) = v;
  }
}

// Fused per-tile MLP, swapped-operand form (byte-identical to R8, 123.8us).
// Block = 256 threads (4 waves), tile = 64 rows. GEMM1: H^T = W1^T @ X^T,
// lane holds 4 consecutive hid -> packed 8B Hs writes. GEMM2: Y^T = W2^T @ H^T
// -> float4 epilogue stores. LDS: Xs 64x280 + Hs[2] 64x152 = 74752B, 2 blk/CU.
#define XS_STRIDE 280
#define HS_STRIDE 152
__global__ __launch_bounds__(256, 2) void fused_kernel(
    const float* __restrict__ x, const int* __restrict__ cntArr,
    const int* __restrict__ bucket, const short* __restrict__ w1sw,
    const short* __restrict__ w2sw, const float* __restrict__ b1,
    const float* __restrict__ b2, float* __restrict__ out) {
  int bid = blockIdx.x;
  // XCD swizzle: bid%8 round-robins XCDs; give species s to XCD pair {2s,2s+1}
  // so each XCD L2 only holds ~1MB of weight fragments.
  int s = (bid & 7) >> 1;
  int t = ((bid >> 3) << 1) | (bid & 1);
  int cnt = cntArr[s * 16];
  int r0 = t * 64;
  if (r0 >= cnt) return;
  int nrows = min(64, cnt - r0);
  const int* buck = bucket + s * N_ATOMS + r0;

  __shared__ short Xs[64 * XS_STRIDE];
  __shared__ short Hs[2][64 * HS_STRIDE];

  int tid = threadIdx.x;

  // Stage gathered x tile -> bf16 LDS (cvt_pk packed). 2048 8-elem groups.
  for (int i = 0; i < 8; ++i) {
    int id = tid + i * 256;
    int r = id >> 5;          // row 0..63
    int g = id & 31;          // 8-float group
    float4 f0 = {}, f1 = {};
    if (r < nrows) {
      const float4* src = (const float4*)(x + (size_t)buck[r] * D_IN + g * 8);
      f0 = src[0];
      f1 = src[1];
    }
    uint4e v;
    v.x = cvt_pk_bf16(f0.x, f0.y);
    v.y = cvt_pk_bf16(f0.z, f0.w);
    v.z = cvt_pk_bf16(f1.x, f1.y);
    v.w = cvt_pk_bf16(f1.z, f1.w);
    *(uint4e*)(Xs + r * XS_STRIDE + g * 8) = v;
  }

  int lane = tid & 63;
  int wid = tid >> 6;
  int lr = lane & 15;          // row within 16-tile (X-row in swapped form)
  int lk = (lane >> 4) * 8;    // k base within 32-kstep
  int lq = (lane >> 4) * 4;    // hid/out base within 16-tile

  // Row gather indices for the epilogue (per bt tile).
  int rowIdx[4];
  #pragma unroll
  for (int bt = 0; bt < 4; ++bt) {
    int r = bt * 16 + lr;
    rowIdx[bt] = (r < nrows) ? buck[r] : -1;
  }

  // accY init = b2 bias (folded). Wave covers out cols [wid*64, wid*64+64).
  float4e accY[4][4];
  #pragma unroll
  for (int at = 0; at < 4; ++at) {
    float4e bv = *(const float4e*)(b2 + s * D_OUT + wid * 64 + at * 16 + lq);
    #pragma unroll
    for (int bt = 0; bt < 4; ++bt) accY[at][bt] = bv;
  }

  // Preload GEMM1 W1-fragments for c=0 (16 batched loads, one latency exposure).
  short8 b1f[16];
  #pragma unroll
  for (int ks = 0; ks < 8; ++ks)
    #pragma unroll
    for (int at = 0; at < 2; ++at) {
      int nt = 0 * 8 + wid * 2 + at;
      b1f[ks * 2 + at] = *(const short8*)(w1sw + ((size_t)((s * 64 + nt) * 8 + ks)) * 512 + lane * 8);
    }

  __syncthreads();   // Xs ready

  for (int c = 0; c < 8; ++c) {
    // acc1 init = b1 bias for this chunk's hid slice.
    float4e acc1[2][4];
    #pragma unroll
    for (int at = 0; at < 2; ++at) {
      float4e bv = *(const float4e*)(b1 + s * D_HID + c * 128 + wid * 32 + at * 16 + lq);
      #pragma unroll
      for (int bt = 0; bt < 4; ++bt) acc1[at][bt] = bv;
    }
    // ---- GEMM1: H^T chunk [128 hid x 64 rows] = W1^T @ X^T ----
    __builtin_amdgcn_s_setprio(1);
    #pragma unroll
    for (int ks = 0; ks < 8; ++ks) {
      short8 xb[4];
      #pragma unroll
      for (int bt = 0; bt < 4; ++bt)
        xb[bt] = *(const short8*)(Xs + (bt * 16 + lr) * XS_STRIDE + ks * 32 + lk);
      #pragma unroll
      for (int at = 0; at < 2; ++at)
        #pragma unroll
        for (int bt = 0; bt < 4; ++bt)
          acc1[at][bt] = __builtin_amdgcn_mfma_f32_16x16x32_bf16(b1f[ks * 2 + at], xb[bt], acc1[at][bt], 0, 0, 0);
    }
    __builtin_amdgcn_s_setprio(0);
    // ---- prefetch GEMM2 W2-fragments (latency hidden under silu+barrier) ----
    short8 b2f[16];
    #pragma unroll
    for (int ks = 0; ks < 4; ++ks)
      #pragma unroll
      for (int at = 0; at < 4; ++at) {
        int nt = wid * 4 + at;
        int kt = c * 4 + ks;
        b2f[ks * 4 + at] = *(const short8*)(w2sw + ((size_t)((s * 16 + nt) * 32 + kt)) * 512 + lane * 8);
      }
    // ---- silu -> Hs[c&1] (cvt_pk packed, 8B writes: 4 consecutive hid/lane) ----
    short* hsb = Hs[c & 1];
    #pragma unroll
    for (int at = 0; at < 2; ++at) {
      int hidloc = wid * 32 + at * 16 + lq;
      #pragma unroll
      for (int bt = 0; bt < 4; ++bt) {
        float4e v4 = acc1[at][bt];
        float sv0 = v4[0] * __builtin_amdgcn_rcpf(1.0f + __expf(-v4[0]));
        float sv1 = v4[1] * __builtin_amdgcn_rcpf(1.0f + __expf(-v4[1]));
        float sv2 = v4[2] * __builtin_amdgcn_rcpf(1.0f + __expf(-v4[2]));
        float sv3 = v4[3] * __builtin_amdgcn_rcpf(1.0f + __expf(-v4[3]));
        uint2e h;
        h.x = cvt_pk_bf16(sv0, sv1);
        h.y = cvt_pk_bf16(sv2, sv3);
        *(uint2e*)(hsb + (bt * 16 + lr) * HS_STRIDE + hidloc) = h;
      }
    }
    __syncthreads();   // Hs[c&1] visible; prior readers of Hs[(c+1)&1] done
    // ---- prefetch next chunk's W1-fragments (hidden under GEMM2 MFMA) ----
    if (c < 7) {
      #pragma unroll
      for (int ks = 0; ks < 8; ++ks)
        #pragma unroll
        for (int at = 0; at < 2; ++at) {
          int nt = (c + 1) * 8 + wid * 2 + at;
          b1f[ks * 2 + at] = *(const short8*)(w1sw + ((size_t)((s * 64 + nt) * 8 + ks)) * 512 + lane * 8);
        }
    }
    // ---- GEMM2 partial: Y^T += W2^T @ H^T ----
    __builtin_amdgcn_s_setprio(1);
    #pragma unroll
    for (int ks = 0; ks < 4; ++ks) {
      short8 hb[4];
      #pragma unroll
      for (int bt = 0; bt < 4; ++bt)
        hb[bt] = *(const short8*)(hsb + (bt * 16 + lr) * HS_STRIDE + ks * 32 + lk);
      #pragma unroll
      for (int at = 0; at < 4; ++at)
        #pragma unroll
        for (int bt = 0; bt < 4; ++bt)
          accY[at][bt] = __builtin_amdgcn_mfma_f32_16x16x32_bf16(b2f[ks * 4 + at], hb[bt], accY[at][bt], 0, 0, 0);
    }
    __builtin_amdgcn_s_setprio(0);
  }

  // ---- epilogue: scatter Y rows, 16B per lane (bias already folded in) ----
  #pragma unroll
  for (int at = 0; at < 4; ++at) {
    int nb = wid * 64 + at * 16 + lq;
    #pragma unroll
    for (int bt = 0; bt < 4; ++bt) {
      if (rowIdx[bt] >= 0)
        *(float4e*)(out + (size_t)rowIdx[bt] * D_OUT + nb) = accY[at][bt];
    }
  }
}

extern "C" void kernel_launch(void* const* d_in, const int* in_sizes, int n_in,
                              void* d_out, int out_size, void* d_ws, size_t ws_size,
                              hipStream_t stream) {
  const float* x  = (const float*)d_in[0];
  const int* spc  = (const int*)d_in[1];
  const float* W1 = (const float*)d_in[2];
  const float* b1 = (const float*)d_in[3];
  const float* W2 = (const float*)d_in[4];
  const float* b2 = (const float*)d_in[5];
  float* out = (float*)d_out;

  int*   cnt    = (int*)d_ws;
  int*   bucket = (int*)((char*)d_ws + WS_BUCKET_OFF);
  short* w1sw   = (short*)((char*)d_ws + WS_W1_OFF);
  short* w2sw   = (short*)((char*)d_ws + WS_W2_OFF);

  prep_count_kernel<<<CF_BLOCKS + 1024, 256, 0, stream>>>(W1, W2, w1sw, w2sw, spc, cnt, bucket);
  fused_kernel<<<4 * TPS, 256, 0, stream>>>(x, cnt, bucket, w1sw, w2sw, b1, b2, out);
}